// Round 2
// baseline (14001.266 us; speedup 1.0000x reference)
//
#include <hip/hip_runtime.h>
#include <stdint.h>

typedef _Float16 f16;
typedef _Float16 f16x8 __attribute__((ext_vector_type(8)));
typedef float f32x4 __attribute__((ext_vector_type(4)));

#define BATCH 256
#define SEQ   128
#define EMB   300
#define HID   1024
#define OUTD  20
#define CAT   1324          // HID + EMB
#define KE    1344          // padded K: 1024 (c) + 320 (x incl bias-1, zero pad)
#define XP    320           // xe row: 300 emb + [300]=1.0 + zeros

__device__ __forceinline__ float sigm(float z)  { return 1.f / (1.f + __expf(-z)); }
__device__ __forceinline__ float tanhf_(float z){ float e = __expf(2.f * z); return 1.f - 2.f / (e + 1.f); }

#define MFMA(a,b,c) __builtin_amdgcn_mfma_f32_16x16x32_f16((a),(b),(c),0,0,0)

// ---------------------------------------------------------------------------
// Weight packing: Wru_e[2048][1344] (rows 0..1023 = W_r|b_r, 1024..2047 = W_u|b_u)
//                 Wc_e[1024][1344], Wp_e[32][1024] (rows >=20 zero)
// ---------------------------------------------------------------------------
__global__ void pack_kernel(const float* __restrict__ Wr, const float* __restrict__ br,
                            const float* __restrict__ Wu, const float* __restrict__ bu,
                            const float* __restrict__ Wc, const float* __restrict__ bc,
                            const float* __restrict__ Wp,
                            f16* __restrict__ Wru_e, f16* __restrict__ Wc_e, f16* __restrict__ Wp_e)
{
    const int NRU = 2048 * KE, NC = 1024 * KE, NP = 32 * HID;
    for (int idx = blockIdx.x * blockDim.x + threadIdx.x; idx < NRU + NC + NP;
         idx += gridDim.x * blockDim.x) {
        if (idx < NRU) {
            int n = idx / KE, k = idx - n * KE;
            const float* Ws = (n < HID) ? Wr : Wu;
            const float* bs = (n < HID) ? br : bu;
            int row = n & (HID - 1);
            float v = (k < CAT) ? Ws[(size_t)row * CAT + k] : ((k == CAT) ? bs[row] : 0.f);
            Wru_e[idx] = (f16)v;
        } else if (idx < NRU + NC) {
            int j = idx - NRU;
            int n = j / KE, k = j - n * KE;
            float v = (k < CAT) ? Wc[(size_t)n * CAT + k] : ((k == CAT) ? bc[n] : 0.f);
            Wc_e[j] = (f16)v;
        } else {
            int j = idx - NRU - NC;
            int n = j / HID, k = j & (HID - 1);
            Wp_e[j] = (n < OUTD) ? (f16)Wp[(size_t)n * HID + k] : (f16)(0.f);
        }
    }
}

// ---------------------------------------------------------------------------
// Embedding gather: xe[t][b][0..319] f16 : emb row, 1.0 at [300], zeros after
// ---------------------------------------------------------------------------
__global__ void gather_kernel(const int* __restrict__ x, const float* __restrict__ emb,
                              f16* __restrict__ xe)
{
    const int TOT = SEQ * BATCH * XP;
    for (int idx = blockIdx.x * blockDim.x + threadIdx.x; idx < TOT;
         idx += gridDim.x * blockDim.x) {
        int e  = idx % XP;
        int rb = idx / XP;            // t*256 + b
        int b  = rb & 255, t = rb >> 8;
        float v;
        if (e < EMB) { int id = x[b * SEQ + t]; v = emb[(size_t)id * EMB + e]; }
        else          v = (e == EMB) ? 1.f : 0.f;
        xe[idx] = (f16)v;
    }
}

__global__ void zero_kernel(uint32_t* __restrict__ c0, int n0, uint32_t* __restrict__ bar, int nb)
{
    for (int i = blockIdx.x * blockDim.x + threadIdx.x; i < n0; i += gridDim.x * blockDim.x)
        c0[i] = 0u;
    if (blockIdx.x == 0 && threadIdx.x < nb) bar[threadIdx.x] = 0u;
}

// ---------------------------------------------------------------------------
// Group barrier: 64 blocks per group, monotonically increasing target.
// Producers: stores ... __threadfence() ... barrier.  Consumers read after.
// ---------------------------------------------------------------------------
__device__ __forceinline__ void group_barrier(int* ctr, int target)
{
    __syncthreads();
    if (threadIdx.x == 0) {
        __hip_atomic_fetch_add(ctr, 1, __ATOMIC_RELEASE, __HIP_MEMORY_SCOPE_AGENT);
        int spins = 0;
        while (__hip_atomic_load(ctr, __ATOMIC_ACQUIRE, __HIP_MEMORY_SCOPE_AGENT) < target) {
            __builtin_amdgcn_s_sleep(2);
            if (++spins > (1 << 22)) break;   // anti-hang valve; never hit in normal operation
        }
    }
    __syncthreads();
}

// ---------------------------------------------------------------------------
// Persistent recurrence. 256 blocks x 256 thr, cooperative launch.
// Group g (blockIdx>>6) owns batch rows [g*64, g*64+64). blk = blockIdx&63.
// Per step: gates (block: 64m x 32n), group barrier, update (64m x 16n),
// group barrier. After t-loop: group-local prediction GEMM.
// Wave wv owns m-tile rows [g*64+wv*16, +16). B-frags shared across waves (L1).
// ---------------------------------------------------------------------------
__global__ __launch_bounds__(256) void rnn_kernel(
    const f16* __restrict__ xe,  const f16* __restrict__ Wru,
    const f16* __restrict__ Wc,  const f16* __restrict__ Wp,
    const float* __restrict__ bpred, f16* __restrict__ Call,
    float* __restrict__ U, f16* __restrict__ RC,
    int* __restrict__ bar, float* __restrict__ out)
{
    const int lane = threadIdx.x & 63;
    const int wv   = threadIdx.x >> 6;
    const int q    = lane >> 4;
    const int cx   = lane & 15;
    const int g    = blockIdx.x >> 6;
    const int blk  = blockIdx.x & 63;
    const int m0   = g * 64 + wv * 16;
    const int ko   = q * 8;
    int* ctr   = bar + g;
    int target = 0;

    for (int t = 0; t < SEQ; ++t) {
        const f16* Ct  = Call + (size_t)t * BATCH * HID;
        f16*       Ct1 = Call + (size_t)(t + 1) * BATCH * HID;
        const f16* xet = xe   + (size_t)t * BATCH * XP;

        // ---- gates: z = [c_prev | x | 1] . Wru^T ; n-cols [blk*32, +32)
        {
            const int  n0 = blk * 32;
            const f16* a1 = Ct  + (size_t)(m0 + cx) * HID + ko;
            const f16* a2 = xet + (size_t)(m0 + cx) * XP  + ko;
            const f16* b0 = Wru + (size_t)(n0 + cx) * KE + ko;
            const f16* b1 = b0 + (size_t)16 * KE;
            f32x4 acc0 = {0.f,0.f,0.f,0.f}, acc1 = {0.f,0.f,0.f,0.f};
            #pragma unroll 4
            for (int kc = 0; kc < 32; ++kc) {
                f16x8 a = *(const f16x8*)(a1 + kc * 32);
                acc0 = MFMA(a, *(const f16x8*)(b0 + kc * 32), acc0);
                acc1 = MFMA(a, *(const f16x8*)(b1 + kc * 32), acc1);
            }
            #pragma unroll 2
            for (int kc = 0; kc < 10; ++kc) {
                f16x8 a = *(const f16x8*)(a2 + kc * 32);
                acc0 = MFMA(a, *(const f16x8*)(b0 + 1024 + kc * 32), acc0);
                acc1 = MFMA(a, *(const f16x8*)(b1 + 1024 + kc * 32), acc1);
            }
            // D mapping: col = cx, row = q*4 + r
            #pragma unroll
            for (int nt = 0; nt < 2; ++nt) {
                int n = n0 + nt * 16 + cx;
                const f32x4& ac = nt ? acc1 : acc0;
                #pragma unroll
                for (int r = 0; r < 4; ++r) {
                    int m = m0 + q * 4 + r;
                    float s = sigm(ac[r]);
                    if (n < HID) {
                        float c = (float)Ct[(size_t)m * HID + n];
                        RC[(size_t)m * HID + n] = (f16)(s * c);
                    } else {
                        U[(size_t)m * HID + (n - HID)] = s;
                    }
                }
            }
        }
        __threadfence();
        target += 64;
        group_barrier(ctr, target);

        // ---- update: cct = tanh([r*c | x | 1] . Wc^T); c' = u*cct + (1-u)*c
        {
            const int  n0 = blk * 16;
            const f16* a1 = RC  + (size_t)(m0 + cx) * HID + ko;
            const f16* a2 = xet + (size_t)(m0 + cx) * XP  + ko;
            const f16* b0 = Wc + (size_t)(n0 + cx) * KE + ko;
            f32x4 acc = {0.f,0.f,0.f,0.f};
            #pragma unroll 4
            for (int kc = 0; kc < 32; ++kc) {
                f16x8 a = *(const f16x8*)(a1 + kc * 32);
                acc = MFMA(a, *(const f16x8*)(b0 + kc * 32), acc);
            }
            #pragma unroll 2
            for (int kc = 0; kc < 10; ++kc) {
                f16x8 a = *(const f16x8*)(a2 + kc * 32);
                acc = MFMA(a, *(const f16x8*)(b0 + 1024 + kc * 32), acc);
            }
            int n = n0 + cx;
            #pragma unroll
            for (int r = 0; r < 4; ++r) {
                int m = m0 + q * 4 + r;
                float u   = U[(size_t)m * HID + n];
                float c   = (float)Ct[(size_t)m * HID + n];
                float cct = tanhf_(acc[r]);
                Ct1[(size_t)m * HID + n] = (f16)(u * cct + (1.f - u) * c);
            }
        }
        __threadfence();
        target += 64;
        group_barrier(ctr, target);
    }

    // ---- prediction: out[b][t][:] = C[t+1][b][:] . Wp^T + bp  (group-local)
    #pragma unroll
    for (int i = 0; i < 2; ++i) {
        int mt = blk * 8 + wv * 2 + i;               // 0..511 local m-tile (16 bt-rows)
        int tt = mt >> 2;                            // time index (const per tile)
        int bb = g * 64 + (mt & 3) * 16 + cx;        // batch row for this lane's A-frag
        const f16* ap  = Call + (size_t)(tt + 1) * BATCH * HID + (size_t)bb * HID + ko;
        const f16* wp0 = Wp + (size_t)cx * HID + ko;
        const f16* wp1 = Wp + (size_t)(16 + cx) * HID + ko;
        f32x4 acc0 = {0.f,0.f,0.f,0.f}, acc1 = {0.f,0.f,0.f,0.f};
        #pragma unroll 4
        for (int kc = 0; kc < 32; ++kc) {
            f16x8 a = *(const f16x8*)(ap + kc * 32);
            acc0 = MFMA(a, *(const f16x8*)(wp0 + kc * 32), acc0);
            acc1 = MFMA(a, *(const f16x8*)(wp1 + kc * 32), acc1);
        }
        #pragma unroll
        for (int nt = 0; nt < 2; ++nt) {
            int o = nt * 16 + cx;
            if (o < OUTD) {
                const f32x4& ac = nt ? acc1 : acc0;
                #pragma unroll
                for (int r = 0; r < 4; ++r) {
                    int rr = mt * 16 + q * 4 + r;
                    int t2 = rr >> 6;
                    int b2 = g * 64 + (rr & 63);
                    out[((size_t)b2 * SEQ + t2) * OUTD + o] = ac[r] + bpred[o];
                }
            }
        }
    }
}

// ---------------------------------------------------------------------------
extern "C" void kernel_launch(void* const* d_in, const int* in_sizes, int n_in,
                              void* d_out, int out_size, void* d_ws, size_t ws_size,
                              hipStream_t stream)
{
    const int*   x   = (const int*)  d_in[0];
    const float* emb = (const float*)d_in[1];
    const float* Wr  = (const float*)d_in[2];
    const float* br  = (const float*)d_in[3];
    const float* Wu  = (const float*)d_in[4];
    const float* bu  = (const float*)d_in[5];
    const float* Wc  = (const float*)d_in[6];
    const float* bc  = (const float*)d_in[7];
    const float* Wp  = (const float*)d_in[8];
    const float* bp  = (const float*)d_in[9];

    char* p = (char*)d_ws;
    f16* Wru_e = (f16*)p;  p += (size_t)2048 * KE * 2;
    f16* Wc_e  = (f16*)p;  p += (size_t)1024 * KE * 2;
    f16* Wp_e  = (f16*)p;  p += (size_t)32 * HID * 2;
    f16* xe    = (f16*)p;  p += (size_t)SEQ * BATCH * XP * 2;
    f16* Call  = (f16*)p;  p += (size_t)(SEQ + 1) * BATCH * HID * 2;  // slot 0 = zeros
    float* U   = (float*)p; p += (size_t)BATCH * HID * 4;
    f16* RC    = (f16*)p;  p += (size_t)BATCH * HID * 2;
    int* bar   = (int*)p;  p += 4 * sizeof(int);

    pack_kernel<<<2048, 256, 0, stream>>>(Wr, br, Wu, bu, Wc, bc, Wp, Wru_e, Wc_e, Wp_e);
    gather_kernel<<<4096, 256, 0, stream>>>(x, emb, xe);
    zero_kernel<<<256, 256, 0, stream>>>((uint32_t*)Call, BATCH * HID / 2, (uint32_t*)bar, 4);

    void* args[] = { &xe, &Wru_e, &Wc_e, &Wp_e, (void*)&bp, &Call, &U, &RC, &bar, &d_out };
    hipLaunchCooperativeKernel((const void*)rnn_kernel, dim3(256), dim3(256),
                               args, 0, stream);
}

// Round 3
// 6121.141 us; speedup vs baseline: 2.2874x; 2.2874x over previous
//
#include <hip/hip_runtime.h>
#include <stdint.h>

typedef _Float16 f16;
typedef _Float16 f16x8 __attribute__((ext_vector_type(8)));
typedef float f32x4 __attribute__((ext_vector_type(4)));

#define BATCH 256
#define SEQ   128
#define EMB   300
#define HID   1024
#define OUTD  20
#define CAT   1324          // HID + EMB
#define KE    1344          // padded K: 1024 (c) + 320 (x incl bias-1, zero pad)
#define XP    320           // xe row: 300 emb + [300]=1.0 + zeros
#define LSTR  1352          // LDS row stride in f16 (676 dwords -> uniform banks)

__device__ __forceinline__ float sigm(float z)  { return 1.f / (1.f + __expf(-z)); }
__device__ __forceinline__ float tanhf_(float z){ float e = __expf(2.f * z); return 1.f - 2.f / (e + 1.f); }

#define MFMA(a,b,c) __builtin_amdgcn_mfma_f32_16x16x32_f16((a),(b),(c),0,0,0)

// ---------------------------------------------------------------------------
// Weight packing: Wru_e[2048][1344] (rows 0..1023 = W_r|b_r, 1024..2047 = W_u|b_u)
//                 Wc_e[1024][1344], Wp_e[32][1024] (rows >=20 zero)
// ---------------------------------------------------------------------------
__global__ void pack_kernel(const float* __restrict__ Wr, const float* __restrict__ br,
                            const float* __restrict__ Wu, const float* __restrict__ bu,
                            const float* __restrict__ Wc, const float* __restrict__ bc,
                            const float* __restrict__ Wp,
                            f16* __restrict__ Wru_e, f16* __restrict__ Wc_e, f16* __restrict__ Wp_e)
{
    const int NRU = 2048 * KE, NC = 1024 * KE, NP = 32 * HID;
    for (int idx = blockIdx.x * blockDim.x + threadIdx.x; idx < NRU + NC + NP;
         idx += gridDim.x * blockDim.x) {
        if (idx < NRU) {
            int n = idx / KE, k = idx - n * KE;
            const float* Ws = (n < HID) ? Wr : Wu;
            const float* bs = (n < HID) ? br : bu;
            int row = n & (HID - 1);
            float v = (k < CAT) ? Ws[(size_t)row * CAT + k] : ((k == CAT) ? bs[row] : 0.f);
            Wru_e[idx] = (f16)v;
        } else if (idx < NRU + NC) {
            int j = idx - NRU;
            int n = j / KE, k = j - n * KE;
            float v = (k < CAT) ? Wc[(size_t)n * CAT + k] : ((k == CAT) ? bc[n] : 0.f);
            Wc_e[j] = (f16)v;
        } else {
            int j = idx - NRU - NC;
            int n = j / HID, k = j & (HID - 1);
            Wp_e[j] = (n < OUTD) ? (f16)Wp[(size_t)n * HID + k] : (f16)(0.f);
        }
    }
}

// ---------------------------------------------------------------------------
// Embedding gather: xe[t][b][0..319] f16 : emb row, 1.0 at [300], zeros after
// ---------------------------------------------------------------------------
__global__ void gather_kernel(const int* __restrict__ x, const float* __restrict__ emb,
                              f16* __restrict__ xe)
{
    const int TOT = SEQ * BATCH * XP;
    for (int idx = blockIdx.x * blockDim.x + threadIdx.x; idx < TOT;
         idx += gridDim.x * blockDim.x) {
        int e  = idx % XP;
        int rb = idx / XP;            // t*256 + b
        int b  = rb & 255, t = rb >> 8;
        float v;
        if (e < EMB) { int id = x[b * SEQ + t]; v = emb[(size_t)id * EMB + e]; }
        else          v = (e == EMB) ? 1.f : 0.f;
        xe[idx] = (f16)v;
    }
}

__global__ void zero_kernel(uint32_t* __restrict__ c0, int n0, uint32_t* __restrict__ bar, int nb)
{
    for (int i = blockIdx.x * blockDim.x + threadIdx.x; i < n0; i += gridDim.x * blockDim.x)
        c0[i] = 0u;
    if (blockIdx.x == 0 && threadIdx.x < nb) bar[threadIdx.x] = 0u;
}

// ---------------------------------------------------------------------------
// Split group barrier (64 blocks/group). Relaxed spin — NO per-iteration
// cache invalidate. Exactly one release-wb and one acquire-inv per barrier.
// __syncthreads() before arrive guarantees all waves' stores have left the CU
// (compiler drains vmcnt before s_barrier).
// ---------------------------------------------------------------------------
__device__ __forceinline__ void bar_arrive(int* ctr)
{
    __syncthreads();
    if (threadIdx.x == 0) {
        __builtin_amdgcn_fence(__ATOMIC_RELEASE, "agent");
        __hip_atomic_fetch_add(ctr, 1, __ATOMIC_RELAXED, __HIP_MEMORY_SCOPE_AGENT);
    }
}
__device__ __forceinline__ void bar_wait(int* ctr, int target)
{
    if (threadIdx.x == 0) {
        int spins = 0;
        while (__hip_atomic_load(ctr, __ATOMIC_RELAXED, __HIP_MEMORY_SCOPE_AGENT) < target) {
            __builtin_amdgcn_s_sleep(1);
            if (++spins > (1 << 24)) break;   // anti-hang valve
        }
        __builtin_amdgcn_fence(__ATOMIC_ACQUIRE, "agent");
    }
    __syncthreads();
}

// ---------------------------------------------------------------------------
// Persistent recurrence. 256 blocks x 256 thr, cooperative.
// Group g = blockIdx>>6 owns batch rows [g*64, +64). blk = blockIdx&63.
// Block's weight slices live in LDS for the whole kernel:
//   ldsRU: Wru rows [blk*32, +32)  (gates),  ldsC: Wc rows [blk*16, +16).
// Per step: gates (64m x 32n) | bar1 | update (64m x 16n) | bar2.
// x-part MFMAs of the NEXT phase run between arrive and wait (xe immutable).
// ---------------------------------------------------------------------------
__global__ __launch_bounds__(256) void rnn_kernel(
    const f16* __restrict__ xe,  const f16* __restrict__ Wru,
    const f16* __restrict__ Wc,  const f16* __restrict__ Wp,
    const float* __restrict__ bpred, f16* __restrict__ Call,
    float* __restrict__ U, f16* __restrict__ RC,
    int* __restrict__ bar, float* __restrict__ out)
{
    extern __shared__ char smem[];
    f16* ldsRU = (f16*)smem;                    // 32 x LSTR
    f16* ldsC  = ldsRU + 32 * LSTR;             // 16 x LSTR

    const int lane = threadIdx.x & 63;
    const int wv   = threadIdx.x >> 6;
    const int q    = lane >> 4;
    const int cx   = lane & 15;
    const int g    = blockIdx.x >> 6;
    const int blk  = blockIdx.x & 63;
    const int m0   = g * 64 + wv * 16;
    const int ko   = q * 8;
    int* ctr   = bar + g;
    int target = 0;

    // ---- stage weight slices into LDS (once) --------------------------------
    {
        const f16* gRU = Wru + (size_t)(blk * 32) * KE;
        for (int i = threadIdx.x; i < 32 * (KE / 8); i += 256) {
            int r = i / (KE / 8), c = i % (KE / 8);
            *(f16x8*)(ldsRU + r * LSTR + c * 8) = *(const f16x8*)(gRU + (size_t)r * KE + c * 8);
        }
        const f16* gC = Wc + (size_t)(blk * 16) * KE;
        for (int i = threadIdx.x; i < 16 * (KE / 8); i += 256) {
            int r = i / (KE / 8), c = i % (KE / 8);
            *(f16x8*)(ldsC + r * LSTR + c * 8) = *(const f16x8*)(gC + (size_t)r * KE + c * 8);
        }
        __syncthreads();
    }

    // LDS B-frag bases (row = local n col)
    const f16* bru0 = ldsRU + (size_t)cx * LSTR + ko;              // n-tile 0
    const f16* bru1 = bru0 + (size_t)16 * LSTR;                    // n-tile 1
    const f16* bc0  = ldsC  + (size_t)cx * LSTR + ko;

    // ---- prologue: gates x-part for t=0 ------------------------------------
    f32x4 gx0 = {0.f,0.f,0.f,0.f}, gx1 = {0.f,0.f,0.f,0.f};
    {
        const f16* a2 = xe + (size_t)(m0 + cx) * XP + ko;
        #pragma unroll
        for (int kc = 0; kc < 10; ++kc) {
            f16x8 a = *(const f16x8*)(a2 + kc * 32);
            gx0 = MFMA(a, *(const f16x8*)(bru0 + 1024 + kc * 32), gx0);
            gx1 = MFMA(a, *(const f16x8*)(bru1 + 1024 + kc * 32), gx1);
        }
    }

    for (int t = 0; t < SEQ; ++t) {
        const f16* Ct  = Call + (size_t)t * BATCH * HID;
        f16*       Ct1 = Call + (size_t)(t + 1) * BATCH * HID;
        const f16* xet = xe   + (size_t)t * BATCH * XP;

        // ---- gates c-part + epilogue ----------------------------------------
        {
            const int  n0 = blk * 32;
            const f16* a1 = Ct + (size_t)(m0 + cx) * HID + ko;
            f32x4 acc0 = gx0, acc1 = gx1;
            #pragma unroll 8
            for (int kc = 0; kc < 32; ++kc) {
                f16x8 a = *(const f16x8*)(a1 + kc * 32);
                acc0 = MFMA(a, *(const f16x8*)(bru0 + kc * 32), acc0);
                acc1 = MFMA(a, *(const f16x8*)(bru1 + kc * 32), acc1);
            }
            // D mapping: col = cx, row = q*4 + r
            #pragma unroll
            for (int nt = 0; nt < 2; ++nt) {
                int n = n0 + nt * 16 + cx;
                const f32x4& ac = nt ? acc1 : acc0;
                #pragma unroll
                for (int r = 0; r < 4; ++r) {
                    int m = m0 + q * 4 + r;
                    float s = sigm(ac[r]);
                    if (n < HID) {
                        float c = (float)Ct[(size_t)m * HID + n];
                        RC[(size_t)m * HID + n] = (f16)(s * c);
                    } else {
                        U[(size_t)m * HID + (n - HID)] = s;
                    }
                }
            }
        }
        target += 64;
        bar_arrive(ctr);

        // ---- update x-part (independent of barrier) -------------------------
        f32x4 ux = {0.f,0.f,0.f,0.f};
        {
            const f16* a2 = xet + (size_t)(m0 + cx) * XP + ko;
            #pragma unroll
            for (int kc = 0; kc < 10; ++kc) {
                f16x8 a = *(const f16x8*)(a2 + kc * 32);
                ux = MFMA(a, *(const f16x8*)(bc0 + 1024 + kc * 32), ux);
            }
        }
        bar_wait(ctr, target);

        // ---- update c-part + epilogue ---------------------------------------
        {
            const int  n0 = blk * 16;
            const f16* a1 = RC + (size_t)(m0 + cx) * HID + ko;
            f32x4 acc = ux;
            #pragma unroll 8
            for (int kc = 0; kc < 32; ++kc) {
                f16x8 a = *(const f16x8*)(a1 + kc * 32);
                acc = MFMA(a, *(const f16x8*)(bc0 + kc * 32), acc);
            }
            int n = n0 + cx;
            #pragma unroll
            for (int r = 0; r < 4; ++r) {
                int m = m0 + q * 4 + r;
                float u   = U[(size_t)m * HID + n];
                float c   = (float)Ct[(size_t)m * HID + n];
                float cct = tanhf_(acc[r]);
                Ct1[(size_t)m * HID + n] = (f16)(u * cct + (1.f - u) * c);
            }
        }
        target += 64;
        bar_arrive(ctr);

        // ---- next gates x-part (independent of barrier) ---------------------
        gx0 = (f32x4){0.f,0.f,0.f,0.f};
        gx1 = (f32x4){0.f,0.f,0.f,0.f};
        if (t + 1 < SEQ) {
            const f16* a2 = xe + (size_t)(t + 1) * BATCH * XP + (size_t)(m0 + cx) * XP + ko;
            #pragma unroll
            for (int kc = 0; kc < 10; ++kc) {
                f16x8 a = *(const f16x8*)(a2 + kc * 32);
                gx0 = MFMA(a, *(const f16x8*)(bru0 + 1024 + kc * 32), gx0);
                gx1 = MFMA(a, *(const f16x8*)(bru1 + 1024 + kc * 32), gx1);
            }
        }
        bar_wait(ctr, target);
    }

    // ---- prediction: out[b][t][:] = C[t+1][b][:] . Wp^T + bp  (group-local)
    #pragma unroll
    for (int i = 0; i < 2; ++i) {
        int mt = blk * 8 + wv * 2 + i;               // 0..511 local m-tile (16 bt-rows)
        int tt = mt >> 2;                            // time index (const per tile)
        int bb = g * 64 + (mt & 3) * 16 + cx;        // batch row for this lane's A-frag
        const f16* ap  = Call + (size_t)(tt + 1) * BATCH * HID + (size_t)bb * HID + ko;
        const f16* wp0 = Wp + (size_t)cx * HID + ko;
        const f16* wp1 = Wp + (size_t)(16 + cx) * HID + ko;
        f32x4 acc0 = {0.f,0.f,0.f,0.f}, acc1 = {0.f,0.f,0.f,0.f};
        #pragma unroll 4
        for (int kc = 0; kc < 32; ++kc) {
            f16x8 a = *(const f16x8*)(ap + kc * 32);
            acc0 = MFMA(a, *(const f16x8*)(wp0 + kc * 32), acc0);
            acc1 = MFMA(a, *(const f16x8*)(wp1 + kc * 32), acc1);
        }
        #pragma unroll
        for (int nt = 0; nt < 2; ++nt) {
            int o = nt * 16 + cx;
            if (o < OUTD) {
                const f32x4& ac = nt ? acc1 : acc0;
                #pragma unroll
                for (int r = 0; r < 4; ++r) {
                    int rr = mt * 16 + q * 4 + r;
                    int t2 = rr >> 6;
                    int b2 = g * 64 + (rr & 63);
                    out[((size_t)b2 * SEQ + t2) * OUTD + o] = ac[r] + bpred[o];
                }
            }
        }
    }
}

// ---------------------------------------------------------------------------
extern "C" void kernel_launch(void* const* d_in, const int* in_sizes, int n_in,
                              void* d_out, int out_size, void* d_ws, size_t ws_size,
                              hipStream_t stream)
{
    const int*   x   = (const int*)  d_in[0];
    const float* emb = (const float*)d_in[1];
    const float* Wr  = (const float*)d_in[2];
    const float* br  = (const float*)d_in[3];
    const float* Wu  = (const float*)d_in[4];
    const float* bu  = (const float*)d_in[5];
    const float* Wc  = (const float*)d_in[6];
    const float* bc  = (const float*)d_in[7];
    const float* Wp  = (const float*)d_in[8];
    const float* bp  = (const float*)d_in[9];

    char* p = (char*)d_ws;
    f16* Wru_e = (f16*)p;  p += (size_t)2048 * KE * 2;
    f16* Wc_e  = (f16*)p;  p += (size_t)1024 * KE * 2;
    f16* Wp_e  = (f16*)p;  p += (size_t)32 * HID * 2;
    f16* xe    = (f16*)p;  p += (size_t)SEQ * BATCH * XP * 2;
    f16* Call  = (f16*)p;  p += (size_t)(SEQ + 1) * BATCH * HID * 2;  // slot 0 = zeros
    float* U   = (float*)p; p += (size_t)BATCH * HID * 4;
    f16* RC    = (f16*)p;  p += (size_t)BATCH * HID * 2;
    int* bar   = (int*)p;  p += 4 * sizeof(int);

    const int LDS_BYTES = 48 * LSTR * 2;   // 129,792

    pack_kernel<<<2048, 256, 0, stream>>>(Wr, br, Wu, bu, Wc, bc, Wp, Wru_e, Wc_e, Wp_e);
    gather_kernel<<<4096, 256, 0, stream>>>(x, emb, xe);
    zero_kernel<<<256, 256, 0, stream>>>((uint32_t*)Call, BATCH * HID / 2, (uint32_t*)bar, 4);

    hipFuncSetAttribute((const void*)rnn_kernel,
                        hipFuncAttributeMaxDynamicSharedMemorySize, LDS_BYTES);

    void* args[] = { &xe, &Wru_e, &Wc_e, &Wp_e, (void*)&bp, &Call, &U, &RC, &bar, &d_out };
    hipLaunchCooperativeKernel((const void*)rnn_kernel, dim3(256), dim3(256),
                               args, LDS_BYTES, stream);
}

// Round 6
// 6041.287 us; speedup vs baseline: 2.3176x; 1.0132x over previous
//
#include <hip/hip_runtime.h>
#include <stdint.h>

typedef _Float16 f16;
typedef _Float16 f16x8 __attribute__((ext_vector_type(8)));
typedef float f32x4 __attribute__((ext_vector_type(4)));

#define BATCH 256
#define SEQ   128
#define EMB   300
#define HID   1024
#define OUTD  20
#define CAT   1324          // HID + EMB
#define KE    1344          // padded K: 1024 (c) + 320 (x incl bias-1, zero pad)
#define XP    320           // xe row: 300 emb + [300]=1.0 + zeros
#define LSTR  1352          // LDS row stride in f16 (16B-aligned rows)

__device__ __forceinline__ float sigm(float z)  { return 1.f / (1.f + __expf(-z)); }
__device__ __forceinline__ float tanhf_(float z){ float e = __expf(2.f * z); return 1.f - 2.f / (e + 1.f); }

#define MFMA(a,b,c) __builtin_amdgcn_mfma_f32_16x16x32_f16((a),(b),(c),0,0,0)

// ---------------------------------------------------------------------------
// Weight packing: Wru_e[2048][1344] (rows 0..1023 = W_r|b_r, 1024..2047 = W_u|b_u)
//                 Wc_e[1024][1344], Wp_e[32][1024] (rows >=20 zero)
// ---------------------------------------------------------------------------
__global__ void pack_kernel(const float* __restrict__ Wr, const float* __restrict__ br,
                            const float* __restrict__ Wu, const float* __restrict__ bu,
                            const float* __restrict__ Wc, const float* __restrict__ bc,
                            const float* __restrict__ Wp,
                            f16* __restrict__ Wru_e, f16* __restrict__ Wc_e, f16* __restrict__ Wp_e)
{
    const int NRU = 2048 * KE, NC = 1024 * KE, NP = 32 * HID;
    for (int idx = blockIdx.x * blockDim.x + threadIdx.x; idx < NRU + NC + NP;
         idx += gridDim.x * blockDim.x) {
        if (idx < NRU) {
            int n = idx / KE, k = idx - n * KE;
            const float* Ws = (n < HID) ? Wr : Wu;
            const float* bs = (n < HID) ? br : bu;
            int row = n & (HID - 1);
            float v = (k < CAT) ? Ws[(size_t)row * CAT + k] : ((k == CAT) ? bs[row] : 0.f);
            Wru_e[idx] = (f16)v;
        } else if (idx < NRU + NC) {
            int j = idx - NRU;
            int n = j / KE, k = j - n * KE;
            float v = (k < CAT) ? Wc[(size_t)n * CAT + k] : ((k == CAT) ? bc[n] : 0.f);
            Wc_e[j] = (f16)v;
        } else {
            int j = idx - NRU - NC;
            int n = j / HID, k = j & (HID - 1);
            Wp_e[j] = (n < OUTD) ? (f16)Wp[(size_t)n * HID + k] : (f16)(0.f);
        }
    }
}

// ---------------------------------------------------------------------------
// Embedding gather: xe[t][b][0..319] f16 : emb row, 1.0 at [300], zeros after
// ---------------------------------------------------------------------------
__global__ void gather_kernel(const int* __restrict__ x, const float* __restrict__ emb,
                              f16* __restrict__ xe)
{
    const int TOT = SEQ * BATCH * XP;
    for (int idx = blockIdx.x * blockDim.x + threadIdx.x; idx < TOT;
         idx += gridDim.x * blockDim.x) {
        int e  = idx % XP;
        int rb = idx / XP;            // t*256 + b
        int b  = rb & 255, t = rb >> 8;
        float v;
        if (e < EMB) { int id = x[b * SEQ + t]; v = emb[(size_t)id * EMB + e]; }
        else          v = (e == EMB) ? 1.f : 0.f;
        xe[idx] = (f16)v;
    }
}

__global__ void zero_kernel(uint32_t* __restrict__ c0, int n0, uint32_t* __restrict__ bar, int nb)
{
    for (int i = blockIdx.x * blockDim.x + threadIdx.x; i < n0; i += gridDim.x * blockDim.x)
        c0[i] = 0u;
    if (blockIdx.x == 0 && threadIdx.x < nb) bar[threadIdx.x] = 0u;
}

// ---------------------------------------------------------------------------
// PROVEN group barrier (round 3 semantics, verbatim): arrive = release-fence +
// relaxed RMW on the group's counter; wait = relaxed spin on the SAME counter
// + acquire fence.
// ---------------------------------------------------------------------------
__device__ __forceinline__ void bar_arrive(int* ctr)
{
    __syncthreads();
    if (threadIdx.x == 0) {
        __builtin_amdgcn_fence(__ATOMIC_RELEASE, "agent");
        __hip_atomic_fetch_add(ctr, 1, __ATOMIC_RELAXED, __HIP_MEMORY_SCOPE_AGENT);
    }
}
__device__ __forceinline__ void bar_wait(int* ctr, int target)
{
    if (threadIdx.x == 0) {
        int spins = 0;
        while (__hip_atomic_load(ctr, __ATOMIC_RELAXED, __HIP_MEMORY_SCOPE_AGENT) < target) {
            __builtin_amdgcn_s_sleep(1);
            if (++spins > (1 << 24)) break;   // anti-hang valve
        }
        __builtin_amdgcn_fence(__ATOMIC_ACQUIRE, "agent");
    }
    __syncthreads();
}

// ---------------------------------------------------------------------------
// Persistent recurrence. 256 blocks x 256 thr, cooperative. Round-3 structure;
// only the c-part K-loops changed: flat abuf[16], 2 batches of 16 independent
// loads each (memory-level parallelism; was 1 dependent load per MFMA pair).
// ---------------------------------------------------------------------------
__global__ __launch_bounds__(256) void rnn_kernel(
    const f16* __restrict__ xe,  const f16* __restrict__ Wru,
    const f16* __restrict__ Wc,  const f16* __restrict__ Wp,
    const float* __restrict__ bpred, f16* __restrict__ Call,
    float* __restrict__ U, f16* __restrict__ RC,
    int* __restrict__ bar, float* __restrict__ out)
{
    extern __shared__ char smem[];
    f16* ldsRU = (f16*)smem;                    // 32 x LSTR
    f16* ldsC  = ldsRU + 32 * LSTR;             // 16 x LSTR

    const int lane = threadIdx.x & 63;
    const int wv   = threadIdx.x >> 6;
    const int q    = lane >> 4;
    const int cx   = lane & 15;
    const int g    = blockIdx.x >> 6;
    const int blk  = blockIdx.x & 63;
    const int m0   = g * 64 + wv * 16;
    const int ko   = q * 8;
    int* ctr   = bar + g;
    int target = 0;

    // ---- stage weight slices into LDS (once) --------------------------------
    {
        const f16* gRU = Wru + (size_t)(blk * 32) * KE;
        for (int i = threadIdx.x; i < 32 * (KE / 8); i += 256) {
            int r = i / (KE / 8), c = i % (KE / 8);
            *(f16x8*)(ldsRU + r * LSTR + c * 8) = *(const f16x8*)(gRU + (size_t)r * KE + c * 8);
        }
        const f16* gC = Wc + (size_t)(blk * 16) * KE;
        for (int i = threadIdx.x; i < 16 * (KE / 8); i += 256) {
            int r = i / (KE / 8), c = i % (KE / 8);
            *(f16x8*)(ldsC + r * LSTR + c * 8) = *(const f16x8*)(gC + (size_t)r * KE + c * 8);
        }
        __syncthreads();
    }

    const f16* bru0 = ldsRU + (size_t)cx * LSTR + ko;              // n-tile 0
    const f16* bru1 = bru0 + (size_t)16 * LSTR;                    // n-tile 1
    const f16* bc0  = ldsC  + (size_t)cx * LSTR + ko;

    // ---- prologue: gates x-part for t=0 ------------------------------------
    f32x4 gx0 = {0.f,0.f,0.f,0.f}, gx1 = {0.f,0.f,0.f,0.f};
    {
        const f16* a2 = xe + (size_t)(m0 + cx) * XP + ko;
        #pragma unroll
        for (int kc = 0; kc < 10; ++kc) {
            f16x8 a = *(const f16x8*)(a2 + kc * 32);
            gx0 = MFMA(a, *(const f16x8*)(bru0 + 1024 + kc * 32), gx0);
            gx1 = MFMA(a, *(const f16x8*)(bru1 + 1024 + kc * 32), gx1);
        }
    }

    for (int t = 0; t < SEQ; ++t) {
        const f16* Ct  = Call + (size_t)t * BATCH * HID;
        f16*       Ct1 = Call + (size_t)(t + 1) * BATCH * HID;
        const f16* xet = xe   + (size_t)t * BATCH * XP;

        // ---- gates c-part + epilogue ----------------------------------------
        {
            const int  n0 = blk * 32;
            const f16* a1 = Ct + (size_t)(m0 + cx) * HID + ko;
            f32x4 acc0 = gx0, acc1 = gx1;
            f16x8 abuf[16];
            #pragma unroll
            for (int h = 0; h < 2; ++h) {
                #pragma unroll
                for (int i = 0; i < 16; ++i)
                    abuf[i] = *(const f16x8*)(a1 + (h * 16 + i) * 32);
                #pragma unroll
                for (int i = 0; i < 16; ++i) {
                    const int kc = h * 16 + i;
                    acc0 = MFMA(abuf[i], *(const f16x8*)(bru0 + kc * 32), acc0);
                    acc1 = MFMA(abuf[i], *(const f16x8*)(bru1 + kc * 32), acc1);
                }
            }
            // D mapping: col = cx, row = q*4 + r
            #pragma unroll
            for (int nt = 0; nt < 2; ++nt) {
                int n = n0 + nt * 16 + cx;
                const f32x4& ac = nt ? acc1 : acc0;
                #pragma unroll
                for (int r = 0; r < 4; ++r) {
                    int m = m0 + q * 4 + r;
                    float s = sigm(ac[r]);
                    if (n < HID) {
                        float c = (float)Ct[(size_t)m * HID + n];
                        RC[(size_t)m * HID + n] = (f16)(s * c);
                    } else {
                        U[(size_t)m * HID + (n - HID)] = s;
                    }
                }
            }
        }
        target += 64;
        bar_arrive(ctr);

        // ---- update x-part (overlaps barrier) -------------------------------
        f32x4 ux = {0.f,0.f,0.f,0.f};
        {
            const f16* a2 = xet + (size_t)(m0 + cx) * XP + ko;
            #pragma unroll
            for (int kc = 0; kc < 10; ++kc) {
                f16x8 a = *(const f16x8*)(a2 + kc * 32);
                ux = MFMA(a, *(const f16x8*)(bc0 + 1024 + kc * 32), ux);
            }
        }
        bar_wait(ctr, target);

        // ---- update c-part + epilogue ---------------------------------------
        {
            const int  n0 = blk * 16;
            const f16* a1 = RC + (size_t)(m0 + cx) * HID + ko;
            f32x4 acc = ux;
            f16x8 abuf[16];
            #pragma unroll
            for (int h = 0; h < 2; ++h) {
                #pragma unroll
                for (int i = 0; i < 16; ++i)
                    abuf[i] = *(const f16x8*)(a1 + (h * 16 + i) * 32);
                #pragma unroll
                for (int i = 0; i < 16; ++i) {
                    const int kc = h * 16 + i;
                    acc = MFMA(abuf[i], *(const f16x8*)(bc0 + kc * 32), acc);
                }
            }
            int n = n0 + cx;
            #pragma unroll
            for (int r = 0; r < 4; ++r) {
                int m = m0 + q * 4 + r;
                float u   = U[(size_t)m * HID + n];
                float c   = (float)Ct[(size_t)m * HID + n];
                float cct = tanhf_(acc[r]);
                Ct1[(size_t)m * HID + n] = (f16)(u * cct + (1.f - u) * c);
            }
        }
        target += 64;
        bar_arrive(ctr);

        // ---- next gates x-part (overlaps barrier) ---------------------------
        gx0 = (f32x4){0.f,0.f,0.f,0.f};
        gx1 = (f32x4){0.f,0.f,0.f,0.f};
        if (t + 1 < SEQ) {
            const f16* a2 = xe + (size_t)(t + 1) * BATCH * XP + (size_t)(m0 + cx) * XP + ko;
            #pragma unroll
            for (int kc = 0; kc < 10; ++kc) {
                f16x8 a = *(const f16x8*)(a2 + kc * 32);
                gx0 = MFMA(a, *(const f16x8*)(bru0 + 1024 + kc * 32), gx0);
                gx1 = MFMA(a, *(const f16x8*)(bru1 + 1024 + kc * 32), gx1);
            }
        }
        bar_wait(ctr, target);
    }

    // ---- prediction: out[b][t][:] = C[t+1][b][:] . Wp^T + bp  (group-local)
    #pragma unroll
    for (int i = 0; i < 2; ++i) {
        int mt = blk * 8 + wv * 2 + i;               // 0..511 local m-tile (16 bt-rows)
        int tt = mt >> 2;                            // time index (const per tile)
        int bb = g * 64 + (mt & 3) * 16 + cx;        // batch row for this lane's A-frag
        const f16* ap  = Call + (size_t)(tt + 1) * BATCH * HID + (size_t)bb * HID + ko;
        const f16* wp0 = Wp + (size_t)cx * HID + ko;
        const f16* wp1 = Wp + (size_t)(16 + cx) * HID + ko;
        f32x4 acc0 = {0.f,0.f,0.f,0.f}, acc1 = {0.f,0.f,0.f,0.f};
        f16x8 abuf[16];
        #pragma unroll
        for (int h = 0; h < 2; ++h) {
            #pragma unroll
            for (int j = 0; j < 16; ++j)
                abuf[j] = *(const f16x8*)(ap + (h * 16 + j) * 32);
            #pragma unroll
            for (int j = 0; j < 16; ++j) {
                const int kc = h * 16 + j;
                acc0 = MFMA(abuf[j], *(const f16x8*)(wp0 + kc * 32), acc0);
                acc1 = MFMA(abuf[j], *(const f16x8*)(wp1 + kc * 32), acc1);
            }
        }
        #pragma unroll
        for (int nt = 0; nt < 2; ++nt) {
            int o = nt * 16 + cx;
            if (o < OUTD) {
                const f32x4& ac = nt ? acc1 : acc0;
                #pragma unroll
                for (int r = 0; r < 4; ++r) {
                    int rr = mt * 16 + q * 4 + r;
                    int t2 = rr >> 6;
                    int b2 = g * 64 + (rr & 63);
                    out[((size_t)b2 * SEQ + t2) * OUTD + o] = ac[r] + bpred[o];
                }
            }
        }
    }
}

// ---------------------------------------------------------------------------
extern "C" void kernel_launch(void* const* d_in, const int* in_sizes, int n_in,
                              void* d_out, int out_size, void* d_ws, size_t ws_size,
                              hipStream_t stream)
{
    const int*   x   = (const int*)  d_in[0];
    const float* emb = (const float*)d_in[1];
    const float* Wr  = (const float*)d_in[2];
    const float* br  = (const float*)d_in[3];
    const float* Wu  = (const float*)d_in[4];
    const float* bu  = (const float*)d_in[5];
    const float* Wc  = (const float*)d_in[6];
    const float* bc  = (const float*)d_in[7];
    const float* Wp  = (const float*)d_in[8];
    const float* bp  = (const float*)d_in[9];

    // bar FIRST (16 B) so barrier counters can never overflow the ws tail.
    char* p = (char*)d_ws;
    int* bar   = (int*)p;  p += 4 * sizeof(int);
    f16* Wru_e = (f16*)p;  p += (size_t)2048 * KE * 2;
    f16* Wc_e  = (f16*)p;  p += (size_t)1024 * KE * 2;
    f16* Wp_e  = (f16*)p;  p += (size_t)32 * HID * 2;
    f16* xe    = (f16*)p;  p += (size_t)SEQ * BATCH * XP * 2;
    f16* Call  = (f16*)p;  p += (size_t)(SEQ + 1) * BATCH * HID * 2;  // slot 0 = zeros
    float* U   = (float*)p; p += (size_t)BATCH * HID * 4;
    f16* RC    = (f16*)p;  p += (size_t)BATCH * HID * 2;

    const int LDS_BYTES = 48 * LSTR * 2;   // 129,792

    pack_kernel<<<2048, 256, 0, stream>>>(Wr, br, Wu, bu, Wc, bc, Wp, Wru_e, Wc_e, Wp_e);
    gather_kernel<<<4096, 256, 0, stream>>>(x, emb, xe);
    zero_kernel<<<256, 256, 0, stream>>>((uint32_t*)Call, BATCH * HID / 2, (uint32_t*)bar, 4);

    hipFuncSetAttribute((const void*)rnn_kernel,
                        hipFuncAttributeMaxDynamicSharedMemorySize, LDS_BYTES);

    void* args[] = { &xe, &Wru_e, &Wc_e, &Wp_e, (void*)&bp, &Call, &U, &RC, &bar, &d_out };
    hipLaunchCooperativeKernel((const void*)rnn_kernel, dim3(256), dim3(256),
                               args, LDS_BYTES, stream);
}

// Round 7
// 4568.874 us; speedup vs baseline: 3.0645x; 1.3223x over previous
//
#include <hip/hip_runtime.h>
#include <stdint.h>

typedef _Float16 f16;
typedef _Float16 f16x8 __attribute__((ext_vector_type(8)));
typedef float f32x4 __attribute__((ext_vector_type(4)));

#define BATCH 256
#define SEQ   128
#define EMB   300
#define HID   1024
#define OUTD  20
#define CAT   1324          // HID + EMB
#define KE    1344          // padded K: 1024 (c) + 320 (x incl bias-1, zero pad)
#define XP    320           // xe row: 300 emb + [300]=1.0 + zeros
#define LSTR  1352          // LDS row stride in f16
#define GRPS  8             // one group per XCD (when mapping is round-robin)
#define BPG   32            // blocks per group
#define MPG   32            // batch rows per group

__device__ __forceinline__ float sigm(float z)  { return 1.f / (1.f + __expf(-z)); }
__device__ __forceinline__ float tanhf_(float z){ float e = __expf(2.f * z); return 1.f - 2.f / (e + 1.f); }

#define MFMA(a,b,c) __builtin_amdgcn_mfma_f32_16x16x32_f16((a),(b),(c),0,0,0)

// ---------------------------------------------------------------------------
// Weight packing: Wru_e[2048][1344] (rows 0..1023 = W_r|b_r, 1024..2047 = W_u|b_u)
//                 Wc_e[1024][1344], Wp_e[32][1024] (rows >=20 zero)
// ---------------------------------------------------------------------------
__global__ void pack_kernel(const float* __restrict__ Wr, const float* __restrict__ br,
                            const float* __restrict__ Wu, const float* __restrict__ bu,
                            const float* __restrict__ Wc, const float* __restrict__ bc,
                            const float* __restrict__ Wp,
                            f16* __restrict__ Wru_e, f16* __restrict__ Wc_e, f16* __restrict__ Wp_e)
{
    const int NRU = 2048 * KE, NC = 1024 * KE, NP = 32 * HID;
    for (int idx = blockIdx.x * blockDim.x + threadIdx.x; idx < NRU + NC + NP;
         idx += gridDim.x * blockDim.x) {
        if (idx < NRU) {
            int n = idx / KE, k = idx - n * KE;
            const float* Ws = (n < HID) ? Wr : Wu;
            const float* bs = (n < HID) ? br : bu;
            int row = n & (HID - 1);
            float v = (k < CAT) ? Ws[(size_t)row * CAT + k] : ((k == CAT) ? bs[row] : 0.f);
            Wru_e[idx] = (f16)v;
        } else if (idx < NRU + NC) {
            int j = idx - NRU;
            int n = j / KE, k = j - n * KE;
            float v = (k < CAT) ? Wc[(size_t)n * CAT + k] : ((k == CAT) ? bc[n] : 0.f);
            Wc_e[j] = (f16)v;
        } else {
            int j = idx - NRU - NC;
            int n = j / HID, k = j & (HID - 1);
            Wp_e[j] = (n < OUTD) ? (f16)Wp[(size_t)n * HID + k] : (f16)(0.f);
        }
    }
}

// ---------------------------------------------------------------------------
// Embedding gather: xe[t][b][0..319] f16 : emb row, 1.0 at [300], zeros after
// ---------------------------------------------------------------------------
__global__ void gather_kernel(const int* __restrict__ x, const float* __restrict__ emb,
                              f16* __restrict__ xe)
{
    const int TOT = SEQ * BATCH * XP;
    for (int idx = blockIdx.x * blockDim.x + threadIdx.x; idx < TOT;
         idx += gridDim.x * blockDim.x) {
        int e  = idx % XP;
        int rb = idx / XP;            // t*256 + b
        int b  = rb & 255, t = rb >> 8;
        float v;
        if (e < EMB) { int id = x[b * SEQ + t]; v = emb[(size_t)id * EMB + e]; }
        else          v = (e == EMB) ? 1.f : 0.f;
        xe[idx] = (f16)v;
    }
}

__global__ void zero_kernel(uint32_t* __restrict__ c0, int n0, uint32_t* __restrict__ bar, int nb)
{
    for (int i = blockIdx.x * blockDim.x + threadIdx.x; i < n0; i += gridDim.x * blockDim.x)
        c0[i] = 0u;
    if (blockIdx.x == 0)
        for (int i = threadIdx.x; i < nb; i += blockDim.x) bar[i] = 0u;
}

// ---------------------------------------------------------------------------
// Group barrier, relay form. fast==1 (group XCD-pure): no cache-maintenance
// fences — visibility through the shared per-XCD L2 (state uses sc-routed
// volatile accesses; __syncthreads drains vmcnt before the flag store).
// fast==0: full agent fences (correct for any placement):
//   worker: fence(rel) -> flag store; checker: flag loads -> fence(acq) ->
//   fence(rel) -> go store; worker: go load -> fence(acq). Transitive HB.
// ---------------------------------------------------------------------------
__device__ __forceinline__ void bar_arrive(int* slot, int ep, int fast)
{
    __syncthreads();
    if (threadIdx.x == 0) {
        if (!fast) __builtin_amdgcn_fence(__ATOMIC_RELEASE, "agent");
        __hip_atomic_store(slot, ep, __ATOMIC_RELAXED, __HIP_MEMORY_SCOPE_AGENT);
    }
}
__device__ __forceinline__ void bar_check(int* arrg, int* go, int ep, int fast, int lane)
{
    int spins = 0;   // whole wave participates; 32 flags in 2 cachelines
    while (!__all(__hip_atomic_load(&arrg[lane & 31], __ATOMIC_RELAXED,
                                    __HIP_MEMORY_SCOPE_AGENT) >= ep)) {
        __builtin_amdgcn_s_sleep(1);
        if (++spins > (1 << 24)) break;
    }
    if (!fast) {
        __builtin_amdgcn_fence(__ATOMIC_ACQUIRE, "agent");
        __builtin_amdgcn_fence(__ATOMIC_RELEASE, "agent");
    } else {
        __builtin_amdgcn_fence(__ATOMIC_ACQ_REL, "workgroup");
    }
    if (lane == 0)
        __hip_atomic_store(go, ep, __ATOMIC_RELAXED, __HIP_MEMORY_SCOPE_AGENT);
}
__device__ __forceinline__ void bar_wait(int* go, int ep, int fast)
{
    if (threadIdx.x == 0) {
        int spins = 0;
        while (__hip_atomic_load(go, __ATOMIC_RELAXED, __HIP_MEMORY_SCOPE_AGENT) < ep) {
            __builtin_amdgcn_s_sleep(1);
            if (++spins > (1 << 24)) break;
        }
        if (!fast) __builtin_amdgcn_fence(__ATOMIC_ACQUIRE, "agent");
        else       __builtin_amdgcn_fence(__ATOMIC_ACQUIRE, "workgroup");
    }
    __syncthreads();
}

// ---------------------------------------------------------------------------
// K-loop helpers (batched loads for MLP). bp is a generic pointer (LDS or
// global). kloop1v uses volatile A loads (RC is rewritten every step).
// ---------------------------------------------------------------------------
__device__ __forceinline__ void kloop2(const f16* __restrict__ a0, const f16* __restrict__ a1,
                                       const f16* bp, f32x4& acc0, f32x4& acc1)
{
    f16x8 A0[8], A1[8], B[8];
    #pragma unroll
    for (int h = 0; h < 4; ++h) {
        #pragma unroll
        for (int i = 0; i < 8; ++i) {
            const int kc = h * 8 + i;
            A0[i] = *(const f16x8*)(a0 + kc * 32);
            A1[i] = *(const f16x8*)(a1 + kc * 32);
            B[i]  = *(const f16x8*)(bp + kc * 32);
        }
        #pragma unroll
        for (int i = 0; i < 8; ++i) {
            acc0 = MFMA(A0[i], B[i], acc0);
            acc1 = MFMA(A1[i], B[i], acc1);
        }
    }
}
__device__ __forceinline__ void kloop1v(const f16* a, const f16* bp, f32x4& acc)
{
    f16x8 A[8], B[8];
    #pragma unroll
    for (int h = 0; h < 4; ++h) {
        #pragma unroll
        for (int i = 0; i < 8; ++i) {
            const int kc = h * 8 + i;
            A[i] = *(const volatile f16x8*)(a + kc * 32);
            B[i] = *(const f16x8*)(bp + kc * 32);
        }
        #pragma unroll
        for (int i = 0; i < 8; ++i) acc = MFMA(A[i], B[i], acc);
    }
}
__device__ __forceinline__ void xpart2(const f16* xa0, const f16* xa1, const f16* bp,
                                       f32x4& acc0, f32x4& acc1)
{
    #pragma unroll
    for (int kc = 0; kc < 10; ++kc) {
        f16x8 B = *(const f16x8*)(bp + 1024 + kc * 32);
        acc0 = MFMA(*(const f16x8*)(xa0 + kc * 32), B, acc0);
        acc1 = MFMA(*(const f16x8*)(xa1 + kc * 32), B, acc1);
    }
}
__device__ __forceinline__ void xpart1(const f16* xa, const f16* bp, f32x4& acc)
{
    #pragma unroll
    for (int kc = 0; kc < 10; ++kc)
        acc = MFMA(*(const f16x8*)(xa + kc * 32),
                   *(const f16x8*)(bp + 1024 + kc * 32), acc);
}

// ---------------------------------------------------------------------------
// Persistent recurrence, XCD-local groups. 256 blocks x 256 thr, cooperative.
// Group g = blockIdx&7 (round-robin block->XCD => group is XCD-pure; verified
// at runtime via HW_REG_XCC_ID, else agent-fenced fallback).
// Group owns batch rows [g*32,+32). gblk = blockIdx>>3 in [0,32).
// Gates: block n-range [gblk*64,+64); wave wv: n-tile wv (wv<2 from LDS,
// wv>=2 from L2-resident global), both m-tiles. Update: block n-range
// [gblk*32,+32); wave: m-tile wv&1, n-tile wv>>1 (tile0 LDS, tile1 global).
// ---------------------------------------------------------------------------
__global__ __launch_bounds__(256) void rnn_kernel(
    const f16* __restrict__ xe,  const f16* __restrict__ Wru,
    const f16* __restrict__ Wc,  const f16* __restrict__ Wp,
    const float* __restrict__ bpred, f16* __restrict__ Call,
    float* __restrict__ U, f16* __restrict__ RC,
    int* __restrict__ bar, float* __restrict__ out)
{
    extern __shared__ char smem[];
    f16* ldsRU = (f16*)smem;                    // 32 x LSTR : Wru rows [N0,N0+32)
    f16* ldsC  = ldsRU + 32 * LSTR;             // 16 x LSTR : Wc rows [M0,M0+16)

    const int tid  = threadIdx.x;
    const int lane = tid & 63;
    const int wv   = tid >> 6;
    const int q    = lane >> 4;
    const int cx   = lane & 15;
    const int ko   = q * 8;
    const int g    = blockIdx.x & 7;
    const int gblk = blockIdx.x >> 3;
    const int mG   = g * MPG;
    const int N0   = gblk * 64;
    const int M0   = gblk * 32;
    const int jm   = wv & 1;                    // update m-tile

    int* arrg = bar + 64 + g * BPG;             // group arrival flags (32 ints)
    int* slot = arrg + gblk;
    int* go   = bar + 384 + g * 16;             // group go flag (padded line)
    int* xc   = bar + 768;                      // 256 xcc ids

    // ---- publish XCC id, one-time fenced grid barrier, purity check --------
    if (tid == 0) {
        int xcc = (int)__builtin_amdgcn_s_getreg((31 << 11) | 20);  // HW_REG_XCC_ID
        __hip_atomic_store(&xc[blockIdx.x], xcc, __ATOMIC_RELAXED, __HIP_MEMORY_SCOPE_AGENT);
    }
    __syncthreads();
    if (tid == 0) {
        __builtin_amdgcn_fence(__ATOMIC_RELEASE, "agent");
        __hip_atomic_fetch_add(&bar[0], 1, __ATOMIC_RELAXED, __HIP_MEMORY_SCOPE_AGENT);
        int spins = 0;
        while (__hip_atomic_load(&bar[0], __ATOMIC_RELAXED, __HIP_MEMORY_SCOPE_AGENT) < 256) {
            __builtin_amdgcn_s_sleep(1);
            if (++spins > (1 << 24)) break;
        }
        __builtin_amdgcn_fence(__ATOMIC_ACQUIRE, "agent");
    }
    __syncthreads();
    int fast = 1;
    {
        int x0 = xc[g];
        for (int i = 1; i < BPG; ++i) fast &= (xc[g + 8 * i] == x0);
    }

    // ---- stage LDS weight slices (once) ------------------------------------
    {
        const f16* gRU = Wru + (size_t)N0 * KE;
        for (int i = tid; i < 32 * (KE / 8); i += 256) {
            int r = i / (KE / 8), c = i % (KE / 8);
            *(f16x8*)(ldsRU + r * LSTR + c * 8) = *(const f16x8*)(gRU + (size_t)r * KE + c * 8);
        }
        const f16* gC = Wc + (size_t)M0 * KE;
        for (int i = tid; i < 16 * (KE / 8); i += 256) {
            int r = i / (KE / 8), c = i % (KE / 8);
            *(f16x8*)(ldsC + r * LSTR + c * 8) = *(const f16x8*)(gC + (size_t)r * KE + c * 8);
        }
        __syncthreads();
    }

    // B-fragment pointers (wave-uniform source selection)
    const f16* bG = (wv < 2) ? (const f16*)(ldsRU + (size_t)(wv * 16 + cx) * LSTR + ko)
                             : (const f16*)(Wru + (size_t)(N0 + wv * 16 + cx) * KE + ko);
    const f16* bU = (wv < 2) ? (const f16*)(ldsC + (size_t)cx * LSTR + ko)
                             : (const f16*)(Wc + (size_t)(M0 + 16 + cx) * KE + ko);
    const int nG = N0 + wv * 16 + cx;            // gates output column
    const int nU = M0 + (wv >> 1) * 16 + cx;     // update output column

    // ---- prologue: gates x-part for t=0 ------------------------------------
    f32x4 gx0 = {0.f,0.f,0.f,0.f}, gx1 = {0.f,0.f,0.f,0.f};
    xpart2(xe + (size_t)(mG + cx) * XP + ko,
           xe + (size_t)(mG + 16 + cx) * XP + ko, bG, gx0, gx1);

    int ep = 0;
    for (int t = 0; t < SEQ; ++t) {
        const f16* Ct  = Call + (size_t)t * BATCH * HID;
        f16*       Ct1 = Call + (size_t)(t + 1) * BATCH * HID;
        const f16* xet = xe   + (size_t)t * BATCH * XP;

        // ================= gates phase =================
        {
            f32x4 acc0 = gx0, acc1 = gx1;
            kloop2(Ct + (size_t)(mG + cx) * HID + ko,
                   Ct + (size_t)(mG + 16 + cx) * HID + ko, bG, acc0, acc1);
            if (N0 < HID) {           // r-gate -> RC (volatile: rewritten each step)
                #pragma unroll
                for (int jt = 0; jt < 2; ++jt) {
                    const f32x4& ac = jt ? acc1 : acc0;
                    #pragma unroll
                    for (int r = 0; r < 4; ++r) {
                        int m = mG + jt * 16 + q * 4 + r;
                        float c = (float)Ct[(size_t)m * HID + nG];
                        *(volatile f16*)&RC[(size_t)m * HID + nG] = (f16)(sigm(ac[r]) * c);
                    }
                }
            } else {                  // u-gate -> U
                #pragma unroll
                for (int jt = 0; jt < 2; ++jt) {
                    const f32x4& ac = jt ? acc1 : acc0;
                    #pragma unroll
                    for (int r = 0; r < 4; ++r) {
                        int m = mG + jt * 16 + q * 4 + r;
                        *(volatile float*)&U[(size_t)m * HID + (nG - HID)] = sigm(ac[r]);
                    }
                }
            }
        }
        ++ep;
        bar_arrive(slot, ep, fast);
        f32x4 ux = {0.f,0.f,0.f,0.f};                         // overlap: update x-part
        xpart1(xet + (size_t)(mG + jm * 16 + cx) * XP + ko, bU, ux);
        if (gblk == 0 && wv == 0) bar_check(arrg, go, ep, fast, lane);
        bar_wait(go, ep, fast);

        // ================= update phase =================
        {
            f32x4 acc = ux;
            kloop1v(RC + (size_t)(mG + jm * 16 + cx) * HID + ko, bU, acc);
            #pragma unroll
            for (int r = 0; r < 4; ++r) {
                int m = mG + jm * 16 + q * 4 + r;
                float u = *(volatile const float*)&U[(size_t)m * HID + nU];
                float c = (float)Ct[(size_t)m * HID + nU];
                float cct = tanhf_(acc[r]);
                *(volatile f16*)&Ct1[(size_t)m * HID + nU] = (f16)(u * cct + (1.f - u) * c);
            }
        }
        ++ep;
        bar_arrive(slot, ep, fast);
        gx0 = (f32x4){0.f,0.f,0.f,0.f};                       // overlap: next gates x-part
        gx1 = (f32x4){0.f,0.f,0.f,0.f};
        if (t + 1 < SEQ)
            xpart2(xe + (size_t)(t + 1) * BATCH * XP + (size_t)(mG + cx) * XP + ko,
                   xe + (size_t)(t + 1) * BATCH * XP + (size_t)(mG + 16 + cx) * XP + ko,
                   bG, gx0, gx1);
        if (gblk == 0 && wv == 0) bar_check(arrg, go, ep, fast, lane);
        bar_wait(go, ep, fast);
    }

    // ---- prediction (group-local): out[b][t][:] = C[t+1][b][:].Wp^T + bp ---
    #pragma unroll
    for (int i = 0; i < 2; ++i) {
        const int mt = gblk * 8 + wv * 2 + i;    // [0,256) group bt-tile
        const int tt = mt >> 1;
        const int bb = mG + (mt & 1) * 16;
        const f16* ap  = Call + (size_t)(tt + 1) * BATCH * HID + (size_t)(bb + cx) * HID + ko;
        const f16* wp0 = Wp + (size_t)cx * HID + ko;
        const f16* wp1 = Wp + (size_t)(16 + cx) * HID + ko;
        f32x4 acc0 = {0.f,0.f,0.f,0.f}, acc1 = {0.f,0.f,0.f,0.f};
        f16x8 A[8], B0[8], B1[8];
        #pragma unroll
        for (int h = 0; h < 4; ++h) {
            #pragma unroll
            for (int j2 = 0; j2 < 8; ++j2) {
                const int kc = h * 8 + j2;
                A[j2]  = *(const f16x8*)(ap  + kc * 32);
                B0[j2] = *(const f16x8*)(wp0 + kc * 32);
                B1[j2] = *(const f16x8*)(wp1 + kc * 32);
            }
            #pragma unroll
            for (int j2 = 0; j2 < 8; ++j2) {
                acc0 = MFMA(A[j2], B0[j2], acc0);
                acc1 = MFMA(A[j2], B1[j2], acc1);
            }
        }
        #pragma unroll
        for (int nt = 0; nt < 2; ++nt) {
            const int o = nt * 16 + cx;
            if (o < OUTD) {
                const f32x4& ac = nt ? acc1 : acc0;
                #pragma unroll
                for (int r = 0; r < 4; ++r) {
                    const int brow = bb + q * 4 + r;
                    out[((size_t)brow * SEQ + tt) * OUTD + o] = ac[r] + bpred[o];
                }
            }
        }
    }
}

// ---------------------------------------------------------------------------
extern "C" void kernel_launch(void* const* d_in, const int* in_sizes, int n_in,
                              void* d_out, int out_size, void* d_ws, size_t ws_size,
                              hipStream_t stream)
{
    const int*   x   = (const int*)  d_in[0];
    const float* emb = (const float*)d_in[1];
    const float* Wr  = (const float*)d_in[2];
    const float* br  = (const float*)d_in[3];
    const float* Wu  = (const float*)d_in[4];
    const float* bu  = (const float*)d_in[5];
    const float* Wc  = (const float*)d_in[6];
    const float* bc  = (const float*)d_in[7];
    const float* Wp  = (const float*)d_in[8];
    const float* bp  = (const float*)d_in[9];

    // bar region FIRST: [0] setup ctr | [64..320) arrival flags |
    // [384..512) go flags (16-int padded) | [768..1024) xcc ids
    char* p = (char*)d_ws;
    int* bar   = (int*)p;  p += 1024 * sizeof(int);
    f16* Wru_e = (f16*)p;  p += (size_t)2048 * KE * 2;
    f16* Wc_e  = (f16*)p;  p += (size_t)1024 * KE * 2;
    f16* Wp_e  = (f16*)p;  p += (size_t)32 * HID * 2;
    f16* xe    = (f16*)p;  p += (size_t)SEQ * BATCH * XP * 2;
    f16* Call  = (f16*)p;  p += (size_t)(SEQ + 1) * BATCH * HID * 2;  // slot 0 = zeros
    float* U   = (float*)p; p += (size_t)BATCH * HID * 4;
    f16* RC    = (f16*)p;  p += (size_t)BATCH * HID * 2;

    const int LDS_BYTES = 48 * LSTR * 2;   // 129,792

    pack_kernel<<<2048, 256, 0, stream>>>(Wr, br, Wu, bu, Wc, bc, Wp, Wru_e, Wc_e, Wp_e);
    gather_kernel<<<4096, 256, 0, stream>>>(x, emb, xe);
    zero_kernel<<<256, 256, 0, stream>>>((uint32_t*)Call, BATCH * HID / 2, (uint32_t*)bar, 1024);

    hipFuncSetAttribute((const void*)rnn_kernel,
                        hipFuncAttributeMaxDynamicSharedMemorySize, LDS_BYTES);

    void* args[] = { &xe, &Wru_e, &Wc_e, &Wp_e, (void*)&bp, &Call, &U, &RC, &bar, &d_out };
    hipLaunchCooperativeKernel((const void*)rnn_kernel, dim3(256), dim3(256),
                               args, LDS_BYTES, stream);
}

// Round 8
// 4109.559 us; speedup vs baseline: 3.4070x; 1.1118x over previous
//
#include <hip/hip_runtime.h>
#include <stdint.h>

typedef _Float16 f16;
typedef _Float16 f16x8 __attribute__((ext_vector_type(8)));
typedef float f32x4 __attribute__((ext_vector_type(4)));

#define BATCH 256
#define SEQ   128
#define EMB   300
#define HID   1024
#define OUTD  20
#define CAT   1324          // HID + EMB
#define KE    1344          // padded K: 1024 (c) + 320 (x incl bias-1, zero pad)
#define XP    320           // xe row: 300 emb + [300]=1.0 + zeros
#define LSTR  1352          // LDS row stride in f16
#define BPG   32            // blocks per group (== CUs per XCD)
#define MPG   32            // batch rows per group

__device__ __forceinline__ float sigm(float z)  { return 1.f / (1.f + __expf(-z)); }
__device__ __forceinline__ float tanhf_(float z){ float e = __expf(2.f * z); return 1.f - 2.f / (e + 1.f); }

#define MFMA(a,b,c) __builtin_amdgcn_mfma_f32_16x16x32_f16((a),(b),(c),0,0,0)

// ---------------------------------------------------------------------------
// Weight packing: Wru_e[2048][1344] (rows 0..1023 = W_r|b_r, 1024..2047 = W_u|b_u)
//                 Wc_e[1024][1344], Wp_e[32][1024] (rows >=20 zero)
// ---------------------------------------------------------------------------
__global__ void pack_kernel(const float* __restrict__ Wr, const float* __restrict__ br,
                            const float* __restrict__ Wu, const float* __restrict__ bu,
                            const float* __restrict__ Wc, const float* __restrict__ bc,
                            const float* __restrict__ Wp,
                            f16* __restrict__ Wru_e, f16* __restrict__ Wc_e, f16* __restrict__ Wp_e)
{
    const int NRU = 2048 * KE, NC = 1024 * KE, NP = 32 * HID;
    for (int idx = blockIdx.x * blockDim.x + threadIdx.x; idx < NRU + NC + NP;
         idx += gridDim.x * blockDim.x) {
        if (idx < NRU) {
            int n = idx / KE, k = idx - n * KE;
            const float* Ws = (n < HID) ? Wr : Wu;
            const float* bs = (n < HID) ? br : bu;
            int row = n & (HID - 1);
            float v = (k < CAT) ? Ws[(size_t)row * CAT + k] : ((k == CAT) ? bs[row] : 0.f);
            Wru_e[idx] = (f16)v;
        } else if (idx < NRU + NC) {
            int j = idx - NRU;
            int n = j / KE, k = j - n * KE;
            float v = (k < CAT) ? Wc[(size_t)n * CAT + k] : ((k == CAT) ? bc[n] : 0.f);
            Wc_e[j] = (f16)v;
        } else {
            int j = idx - NRU - NC;
            int n = j / HID, k = j & (HID - 1);
            Wp_e[j] = (n < OUTD) ? (f16)Wp[(size_t)n * HID + k] : (f16)(0.f);
        }
    }
}

// ---------------------------------------------------------------------------
// Embedding gather: xe[t][b][0..319] f16 : emb row, 1.0 at [300], zeros after
// ---------------------------------------------------------------------------
__global__ void gather_kernel(const int* __restrict__ x, const float* __restrict__ emb,
                              f16* __restrict__ xe)
{
    const int TOT = SEQ * BATCH * XP;
    for (int idx = blockIdx.x * blockDim.x + threadIdx.x; idx < TOT;
         idx += gridDim.x * blockDim.x) {
        int e  = idx % XP;
        int rb = idx / XP;            // t*256 + b
        int b  = rb & 255, t = rb >> 8;
        float v;
        if (e < EMB) { int id = x[b * SEQ + t]; v = emb[(size_t)id * EMB + e]; }
        else          v = (e == EMB) ? 1.f : 0.f;
        xe[idx] = (f16)v;
    }
}

__global__ void zero_kernel(uint32_t* __restrict__ c0, int n0, uint32_t* __restrict__ bar, int nb)
{
    for (int i = blockIdx.x * blockDim.x + threadIdx.x; i < n0; i += gridDim.x * blockDim.x)
        c0[i] = 0u;
    if (blockIdx.x == 0)
        for (int i = threadIdx.x; i < nb; i += blockDim.x) bar[i] = 0u;
}

// ---------------------------------------------------------------------------
// Dual-mode relay barrier.
// fast==1 (group is XCD-pure BY CONSTRUCTION): flags are volatile words in
// global memory — write-through/sc0 to the XCD's L2 (the intra-XCD coherence
// point). __syncthreads() drains vmcnt before the flag store, so all data
// stores are in L2 first. No cache-maintenance ops at all.
// fast==0: agent-scope atomics + agent fences (correct for any placement).
// ---------------------------------------------------------------------------
__device__ __forceinline__ void bar_arrive(int* slot, int ep, int fast)
{
    __syncthreads();
    if (threadIdx.x == 0) {
        if (fast) {
            *(volatile int*)slot = ep;
        } else {
            __builtin_amdgcn_fence(__ATOMIC_RELEASE, "agent");
            __hip_atomic_store(slot, ep, __ATOMIC_RELAXED, __HIP_MEMORY_SCOPE_AGENT);
        }
    }
}
__device__ __forceinline__ void bar_check(int* arrg, int* go, int ep, int fast, int lane)
{
    int spins = 0;   // whole wave: 32 flags in 2 cachelines
    if (fast) {
        while (!__all(*(volatile int*)&arrg[lane & 31] >= ep)) {
            __builtin_amdgcn_s_sleep(1);
            if (++spins > (1 << 24)) break;
        }
        __builtin_amdgcn_fence(__ATOMIC_ACQ_REL, "workgroup");   // compiler order only
        if (lane == 0) *(volatile int*)go = ep;
    } else {
        while (!__all(__hip_atomic_load(&arrg[lane & 31], __ATOMIC_RELAXED,
                                        __HIP_MEMORY_SCOPE_AGENT) >= ep)) {
            __builtin_amdgcn_s_sleep(1);
            if (++spins > (1 << 24)) break;
        }
        __builtin_amdgcn_fence(__ATOMIC_ACQUIRE, "agent");
        __builtin_amdgcn_fence(__ATOMIC_RELEASE, "agent");
        if (lane == 0)
            __hip_atomic_store(go, ep, __ATOMIC_RELAXED, __HIP_MEMORY_SCOPE_AGENT);
    }
}
__device__ __forceinline__ void bar_wait(int* go, int ep, int fast)
{
    if (threadIdx.x == 0) {
        int spins = 0;
        if (fast) {
            while (*(volatile int*)go < ep) {
                __builtin_amdgcn_s_sleep(1);
                if (++spins > (1 << 24)) break;
            }
            __builtin_amdgcn_fence(__ATOMIC_ACQUIRE, "workgroup");  // compiler order
        } else {
            while (__hip_atomic_load(go, __ATOMIC_RELAXED, __HIP_MEMORY_SCOPE_AGENT) < ep) {
                __builtin_amdgcn_s_sleep(1);
                if (++spins > (1 << 24)) break;
            }
            __builtin_amdgcn_fence(__ATOMIC_ACQUIRE, "agent");
        }
    }
    __syncthreads();
}

// ---------------------------------------------------------------------------
// K-loop helpers (batched loads for MLP). kloop1v: volatile A loads (RC is
// rewritten every step -> must bypass stale L1; sc0 reads hit the XCD L2).
// ---------------------------------------------------------------------------
__device__ __forceinline__ void kloop2(const f16* __restrict__ a0, const f16* __restrict__ a1,
                                       const f16* bp, f32x4& acc0, f32x4& acc1)
{
    f16x8 A0[8], A1[8], B[8];
    #pragma unroll
    for (int h = 0; h < 4; ++h) {
        #pragma unroll
        for (int i = 0; i < 8; ++i) {
            const int kc = h * 8 + i;
            A0[i] = *(const f16x8*)(a0 + kc * 32);
            A1[i] = *(const f16x8*)(a1 + kc * 32);
            B[i]  = *(const f16x8*)(bp + kc * 32);
        }
        #pragma unroll
        for (int i = 0; i < 8; ++i) {
            acc0 = MFMA(A0[i], B[i], acc0);
            acc1 = MFMA(A1[i], B[i], acc1);
        }
    }
}
__device__ __forceinline__ void kloop1v(const f16* a, const f16* bp, f32x4& acc)
{
    f16x8 A[8], B[8];
    #pragma unroll
    for (int h = 0; h < 4; ++h) {
        #pragma unroll
        for (int i = 0; i < 8; ++i) {
            const int kc = h * 8 + i;
            A[i] = *(const volatile f16x8*)(a + kc * 32);
            B[i] = *(const f16x8*)(bp + kc * 32);
        }
        #pragma unroll
        for (int i = 0; i < 8; ++i) acc = MFMA(A[i], B[i], acc);
    }
}
__device__ __forceinline__ void xpart2(const f16* xa0, const f16* xa1, const f16* bp,
                                       f32x4& acc0, f32x4& acc1)
{
    #pragma unroll
    for (int kc = 0; kc < 10; ++kc) {
        f16x8 B = *(const f16x8*)(bp + 1024 + kc * 32);
        acc0 = MFMA(*(const f16x8*)(xa0 + kc * 32), B, acc0);
        acc1 = MFMA(*(const f16x8*)(xa1 + kc * 32), B, acc1);
    }
}
__device__ __forceinline__ void xpart1(const f16* xa, const f16* bp, f32x4& acc)
{
    #pragma unroll
    for (int kc = 0; kc < 10; ++kc)
        acc = MFMA(*(const f16x8*)(xa + kc * 32),
                   *(const f16x8*)(bp + 1024 + kc * 32), acc);
}

// ---------------------------------------------------------------------------
// Persistent recurrence, XCD-pure groups BY CONSTRUCTION. 256 blocks x 256
// thr, cooperative (1 block/CU by LDS). Each block reads XCC_ID and claims a
// rank within its XCD; if every XCD has exactly 32 blocks: group=xcd,
// gblk=rank, fast path. Else fallback blockIdx mapping + agent fences.
// Group owns batch rows [g*32,+32). Gates: block n-cols [gblk*64,+64), wave
// wv = n-tile (wv<2 LDS, wv>=2 L2-global). Update: block n-cols [gblk*32,+32),
// wave: m-tile wv&1, n-tile wv>>1 (tile0 LDS, tile1 global).
// ---------------------------------------------------------------------------
__global__ __launch_bounds__(256) void rnn_kernel(
    const f16* __restrict__ xe,  const f16* __restrict__ Wru,
    const f16* __restrict__ Wc,  const f16* __restrict__ Wp,
    const float* __restrict__ bpred, f16* __restrict__ Call,
    float* __restrict__ U, f16* __restrict__ RC,
    int* __restrict__ bar, float* __restrict__ out)
{
    extern __shared__ char smem[];
    f16* ldsRU = (f16*)smem;                    // 32 x LSTR : Wru rows [N0,N0+32)
    f16* ldsC  = ldsRU + 32 * LSTR;             // 16 x LSTR : Wc rows [M0,M0+16)
    __shared__ int s_g, s_r, s_fast;

    const int tid  = threadIdx.x;
    const int lane = tid & 63;
    const int wv   = tid >> 6;
    const int q    = lane >> 4;
    const int cx   = lane & 15;
    const int ko   = q * 8;

    // ---- claim rank within actual XCD; one-time fenced grid barrier --------
    if (tid == 0) {
        int xcd = (int)__builtin_amdgcn_s_getreg((31 << 11) | 20) & 15;  // HW_REG_XCC_ID
        int r   = __hip_atomic_fetch_add(&bar[xcd], 1, __ATOMIC_RELAXED,
                                         __HIP_MEMORY_SCOPE_AGENT);
        __builtin_amdgcn_fence(__ATOMIC_RELEASE, "agent");
        __hip_atomic_fetch_add(&bar[16], 1, __ATOMIC_RELAXED, __HIP_MEMORY_SCOPE_AGENT);
        int spins = 0;
        while (__hip_atomic_load(&bar[16], __ATOMIC_RELAXED, __HIP_MEMORY_SCOPE_AGENT) < 256) {
            __builtin_amdgcn_s_sleep(1);
            if (++spins > (1 << 24)) break;
        }
        __builtin_amdgcn_fence(__ATOMIC_ACQUIRE, "agent");
        int ok = 1;
        for (int i = 0; i < 8; ++i) ok &= (bar[i] == BPG);
        if (ok) { s_g = xcd; s_r = r; s_fast = 1; }
        else    { s_g = blockIdx.x & 7; s_r = blockIdx.x >> 3; s_fast = 0; }
    }
    __syncthreads();
    const int g    = s_g;
    const int gblk = s_r;
    const int fast = s_fast;
    const int mG   = g * MPG;
    const int N0   = gblk * 64;
    const int M0   = gblk * 32;
    const int jm   = wv & 1;

    int* arrg = bar + 64 + g * BPG;             // group arrival flags (32 ints)
    int* slot = arrg + gblk;
    int* go   = bar + 384 + g * 16;             // group go flag (padded line)

    // ---- stage LDS weight slices (once) ------------------------------------
    {
        const f16* gRU = Wru + (size_t)N0 * KE;
        for (int i = tid; i < 32 * (KE / 8); i += 256) {
            int r = i / (KE / 8), c = i % (KE / 8);
            *(f16x8*)(ldsRU + r * LSTR + c * 8) = *(const f16x8*)(gRU + (size_t)r * KE + c * 8);
        }
        const f16* gC = Wc + (size_t)M0 * KE;
        for (int i = tid; i < 16 * (KE / 8); i += 256) {
            int r = i / (KE / 8), c = i % (KE / 8);
            *(f16x8*)(ldsC + r * LSTR + c * 8) = *(const f16x8*)(gC + (size_t)r * KE + c * 8);
        }
        __syncthreads();
    }

    // B-fragment pointers (wave-uniform source selection)
    const f16* bG = (wv < 2) ? (const f16*)(ldsRU + (size_t)(wv * 16 + cx) * LSTR + ko)
                             : (const f16*)(Wru + (size_t)(N0 + wv * 16 + cx) * KE + ko);
    const f16* bU = (wv < 2) ? (const f16*)(ldsC + (size_t)cx * LSTR + ko)
                             : (const f16*)(Wc + (size_t)(M0 + 16 + cx) * KE + ko);
    const int nG = N0 + wv * 16 + cx;            // gates output column
    const int nU = M0 + (wv >> 1) * 16 + cx;     // update output column
    const int is_chk = (gblk == 0 && wv == 0);

    // ---- prologue: gates x-part for t=0 ------------------------------------
    f32x4 gx0 = {0.f,0.f,0.f,0.f}, gx1 = {0.f,0.f,0.f,0.f};
    xpart2(xe + (size_t)(mG + cx) * XP + ko,
           xe + (size_t)(mG + 16 + cx) * XP + ko, bG, gx0, gx1);

    int ep = 0;
    for (int t = 0; t < SEQ; ++t) {
        const f16* Ct  = Call + (size_t)t * BATCH * HID;
        f16*       Ct1 = Call + (size_t)(t + 1) * BATCH * HID;
        const f16* xet = xe   + (size_t)t * BATCH * XP;

        // ================= gates phase =================
        {
            f32x4 acc0 = gx0, acc1 = gx1;
            kloop2(Ct + (size_t)(mG + cx) * HID + ko,
                   Ct + (size_t)(mG + 16 + cx) * HID + ko, bG, acc0, acc1);
            if (N0 < HID) {           // r-gate -> RC (volatile: rewritten each step)
                #pragma unroll
                for (int jt = 0; jt < 2; ++jt) {
                    const f32x4& ac = jt ? acc1 : acc0;
                    #pragma unroll
                    for (int r = 0; r < 4; ++r) {
                        int m = mG + jt * 16 + q * 4 + r;
                        float c = (float)Ct[(size_t)m * HID + nG];
                        *(volatile f16*)&RC[(size_t)m * HID + nG] = (f16)(sigm(ac[r]) * c);
                    }
                }
            } else {                  // u-gate -> U
                #pragma unroll
                for (int jt = 0; jt < 2; ++jt) {
                    const f32x4& ac = jt ? acc1 : acc0;
                    #pragma unroll
                    for (int r = 0; r < 4; ++r) {
                        int m = mG + jt * 16 + q * 4 + r;
                        *(volatile float*)&U[(size_t)m * HID + (nG - HID)] = sigm(ac[r]);
                    }
                }
            }
        }
        ++ep;
        bar_arrive(slot, ep, fast);
        f32x4 ux = {0.f,0.f,0.f,0.f};
        if (is_chk) {                 // checker first: release others ASAP
            bar_check(arrg, go, ep, fast, lane);
            xpart1(xet + (size_t)(mG + jm * 16 + cx) * XP + ko, bU, ux);
        } else {                      // workers overlap x-part with barrier
            xpart1(xet + (size_t)(mG + jm * 16 + cx) * XP + ko, bU, ux);
        }
        bar_wait(go, ep, fast);

        // ================= update phase =================
        {
            f32x4 acc = ux;
            kloop1v(RC + (size_t)(mG + jm * 16 + cx) * HID + ko, bU, acc);
            #pragma unroll
            for (int r = 0; r < 4; ++r) {
                int m = mG + jm * 16 + q * 4 + r;
                float u = *(volatile const float*)&U[(size_t)m * HID + nU];
                float c = (float)Ct[(size_t)m * HID + nU];
                float cct = tanhf_(acc[r]);
                *(volatile f16*)&Ct1[(size_t)m * HID + nU] = (f16)(u * cct + (1.f - u) * c);
            }
        }
        ++ep;
        bar_arrive(slot, ep, fast);
        gx0 = (f32x4){0.f,0.f,0.f,0.f};
        gx1 = (f32x4){0.f,0.f,0.f,0.f};
        if (is_chk) {
            bar_check(arrg, go, ep, fast, lane);
            if (t + 1 < SEQ)
                xpart2(xe + (size_t)(t + 1) * BATCH * XP + (size_t)(mG + cx) * XP + ko,
                       xe + (size_t)(t + 1) * BATCH * XP + (size_t)(mG + 16 + cx) * XP + ko,
                       bG, gx0, gx1);
        } else {
            if (t + 1 < SEQ)
                xpart2(xe + (size_t)(t + 1) * BATCH * XP + (size_t)(mG + cx) * XP + ko,
                       xe + (size_t)(t + 1) * BATCH * XP + (size_t)(mG + 16 + cx) * XP + ko,
                       bG, gx0, gx1);
        }
        bar_wait(go, ep, fast);
    }

    // ---- prediction (group-local): out[b][t][:] = C[t+1][b][:].Wp^T + bp ---
    #pragma unroll
    for (int i = 0; i < 2; ++i) {
        const int mt = gblk * 8 + wv * 2 + i;    // [0,256) group bt-tile
        const int tt = mt >> 1;
        const int bb = mG + (mt & 1) * 16;
        const f16* ap  = Call + (size_t)(tt + 1) * BATCH * HID + (size_t)(bb + cx) * HID + ko;
        const f16* wp0 = Wp + (size_t)cx * HID + ko;
        const f16* wp1 = Wp + (size_t)(16 + cx) * HID + ko;
        f32x4 acc0 = {0.f,0.f,0.f,0.f}, acc1 = {0.f,0.f,0.f,0.f};
        f16x8 A[8], B0[8], B1[8];
        #pragma unroll
        for (int h = 0; h < 4; ++h) {
            #pragma unroll
            for (int j2 = 0; j2 < 8; ++j2) {
                const int kc = h * 8 + j2;
                A[j2]  = *(const f16x8*)(ap  + kc * 32);
                B0[j2] = *(const f16x8*)(wp0 + kc * 32);
                B1[j2] = *(const f16x8*)(wp1 + kc * 32);
            }
            #pragma unroll
            for (int j2 = 0; j2 < 8; ++j2) {
                acc0 = MFMA(A[j2], B0[j2], acc0);
                acc1 = MFMA(A[j2], B1[j2], acc1);
            }
        }
        #pragma unroll
        for (int nt = 0; nt < 2; ++nt) {
            const int o = nt * 16 + cx;
            if (o < OUTD) {
                const f32x4& ac = nt ? acc1 : acc0;
                #pragma unroll
                for (int r = 0; r < 4; ++r) {
                    const int brow = bb + q * 4 + r;
                    out[((size_t)brow * SEQ + tt) * OUTD + o] = ac[r] + bpred[o];
                }
            }
        }
    }
}

// ---------------------------------------------------------------------------
extern "C" void kernel_launch(void* const* d_in, const int* in_sizes, int n_in,
                              void* d_out, int out_size, void* d_ws, size_t ws_size,
                              hipStream_t stream)
{
    const int*   x   = (const int*)  d_in[0];
    const float* emb = (const float*)d_in[1];
    const float* Wr  = (const float*)d_in[2];
    const float* br  = (const float*)d_in[3];
    const float* Wu  = (const float*)d_in[4];
    const float* bu  = (const float*)d_in[5];
    const float* Wc  = (const float*)d_in[6];
    const float* bc  = (const float*)d_in[7];
    const float* Wp  = (const float*)d_in[8];
    const float* bp  = (const float*)d_in[9];

    // bar region FIRST: [0..16) xcd counts | [16] grid ctr |
    // [64..320) arrival flags | [384..512) go flags (16-int padded)
    char* p = (char*)d_ws;
    int* bar   = (int*)p;  p += 1024 * sizeof(int);
    f16* Wru_e = (f16*)p;  p += (size_t)2048 * KE * 2;
    f16* Wc_e  = (f16*)p;  p += (size_t)1024 * KE * 2;
    f16* Wp_e  = (f16*)p;  p += (size_t)32 * HID * 2;
    f16* xe    = (f16*)p;  p += (size_t)SEQ * BATCH * XP * 2;
    f16* Call  = (f16*)p;  p += (size_t)(SEQ + 1) * BATCH * HID * 2;  // slot 0 = zeros
    float* U   = (float*)p; p += (size_t)BATCH * HID * 4;
    f16* RC    = (f16*)p;  p += (size_t)BATCH * HID * 2;

    const int LDS_BYTES = 48 * LSTR * 2;   // 129,792

    pack_kernel<<<2048, 256, 0, stream>>>(Wr, br, Wu, bu, Wc, bc, Wp, Wru_e, Wc_e, Wp_e);
    gather_kernel<<<4096, 256, 0, stream>>>(x, emb, xe);
    zero_kernel<<<256, 256, 0, stream>>>((uint32_t*)Call, BATCH * HID / 2, (uint32_t*)bar, 1024);

    hipFuncSetAttribute((const void*)rnn_kernel,
                        hipFuncAttributeMaxDynamicSharedMemorySize, LDS_BYTES);

    void* args[] = { &xe, &Wru_e, &Wc_e, &Wp_e, (void*)&bp, &Call, &U, &RC, &bar, &d_out };
    hipLaunchCooperativeKernel((const void*)rnn_kernel, dim3(256), dim3(256),
                               args, LDS_BYTES, stream);
}